// Round 11
// baseline (151.154 us; speedup 1.0000x reference)
//
#include <hip/hip_runtime.h>
#include <math.h>

#define N_PTS     131072
#define G_NUMS    30
#define G_SIZE    100
#define PT_STRIDE (N_PTS / G_NUMS)   // 4369
#define TPB       1024
#define NWAVES    (TPB / 64)         // 16
#define BINS      4096
#define JB        (BINS / TPB)       // 4 bins per thread
#define SHIFT     20
#define SAMPLE_GRPS 1024             // fallback sample: first 4096 pts
#define RANK_CUT  32                 // fallback rank
#define CAP       3072               // survivor capacity
#define TIE_CAP   64
// register-bisection tau: 2048-pt quantized sample, rank-12 => E[S] ~ 770
#define SMP_N     2048
#define SMP_PL    32                 // sample d^2 per lane (2048/64)
#define SMP_CUT   12
#define SMP_ITERS 13
// int16 quantization: [-8,8) in 65536 steps
#define QS16      (1.0f / 4096.0f)
#define QC16      (-8.0f + 0.5f / 4096.0f)   // bin-center offset
#define QM16      3.0e-4f                    // distance error bound (cushioned)

struct KSmem {
    union {
        unsigned hist[BINS];         // 16 KB
        struct {                     // finalize overlay (last block only)
            float gm[256][3];
            float dir[256][3];
            float pe[NWAVES];
            float ps[NWAVES];
        } fin;
    };
    unsigned wsum[NWAVES];
    unsigned T;
    int ns, nd, nt;
    unsigned u[CAP];
    int idx[CAP];
    float px[CAP], py[CAP], pz[CAP]; // survivor coords (exact fp32)
    int sel[G_SIZE];                 // positions into survivor arrays
    unsigned tu[TIE_CAP];
    int ti[TIE_CAP];                 // positions
    float acc[3], cov[6], q[3];
    unsigned tau0, maxu, r1;
    float delta2;
};

__device__ __forceinline__ float dist2f(float px, float py, float pz,
                                        float qx, float qy, float qz) {
    float dx = px - qx, dy = py - qy, dz = pz - qz;
    return fmaf(dx, dx, fmaf(dy, dy, dz * dz));
}

// Find smallest bin T such that cumulative count through T >= rank.
__device__ __forceinline__ unsigned find_bin(KSmem& sm, unsigned rank,
                                             int tid, int lane, int wid) {
    unsigned hv[JB], csum = 0;
#pragma unroll
    for (int j = 0; j < JB; j++) { hv[j] = sm.hist[tid * JB + j]; csum += hv[j]; }
    unsigned inc = csum;
#pragma unroll
    for (int off = 1; off < 64; off <<= 1) {
        unsigned n = __shfl_up(inc, off);
        if (lane >= off) inc += n;
    }
    __syncthreads();                  // protect wsum reuse across calls
    if (lane == 63) sm.wsum[wid] = inc;
    __syncthreads();
    unsigned base = 0;
    for (int w = 0; w < wid; w++) base += sm.wsum[w];
    unsigned c = base + inc - csum;   // exclusive prefix before this thread's chunk
#pragma unroll
    for (int j = 0; j < JB; j++) {
        if (c < rank && c + hv[j] >= rank) sm.T = (unsigned)(tid * JB + j);
        c += hv[j];
    }
    __syncthreads();
    return sm.T;
}

// Exact top-100 select over sm.u[0..min(ns,CAP)) -> sm.sel positions.
// ubound: upper bound (bits) on all u values. hist & nd/nt zeroed on entry.
__device__ void fine_select(KSmem& sm, unsigned ubound, int tid, int lane, int wid) {
    int S = sm.ns; if (S > CAP) S = CAP;
    unsigned hb = 32u - (unsigned)__clz(ubound | 1u);
    unsigned s2 = hb > 12u ? hb - 12u : 0u;
    for (int i = tid; i < S; i += TPB) {
        unsigned bin = sm.u[i] >> s2; if (bin > BINS - 1u) bin = BINS - 1u;
        atomicAdd(&sm.hist[bin], 1u);
    }
    __syncthreads();
    unsigned T2 = find_bin(sm, G_SIZE, tid, lane, wid);
    for (int i = tid; i < S; i += TPB) {
        unsigned uu = sm.u[i];
        unsigned bin = uu >> s2; if (bin > BINS - 1u) bin = BINS - 1u;
        if (bin < T2) {
            int p = atomicAdd(&sm.nd, 1);
            if (p < G_SIZE) sm.sel[p] = i;
        } else if (bin == T2) {
            int p = atomicAdd(&sm.nt, 1);
            if (p < TIE_CAP) { sm.tu[p] = uu; sm.ti[p] = i; }
        }
    }
    __syncthreads();
    if (tid == 0) {
        int nd = sm.nd; if (nd > G_SIZE) nd = G_SIZE;
        int need = G_SIZE - nd;
        int ec = sm.nt; if (ec > TIE_CAP) ec = TIE_CAP;
        for (int a = 0; a < need && a < ec; ++a) {
            int best = a;
            for (int j = a + 1; j < ec; ++j)
                if (sm.tu[j] < sm.tu[best] ||
                    (sm.tu[j] == sm.tu[best] && sm.idx[sm.ti[j]] < sm.idx[sm.ti[best]])) best = j;
            unsigned tub = sm.tu[best]; sm.tu[best] = sm.tu[a]; sm.tu[a] = tub;
            int tib = sm.ti[best]; sm.ti[best] = sm.ti[a]; sm.ti[a] = tib;
            sm.sel[nd + a] = sm.ti[a];
        }
    }
    __syncthreads();
}

// Exact AoS distance+filter+stash for one float4-group (4 points).
__device__ __forceinline__ void push4(KSmem& sm, const float4& xv, const float4& yv,
                                      const float4& zv, int i, unsigned tau,
                                      float qx, float qy, float qz) {
    unsigned u0 = __float_as_uint(dist2f(xv.x, yv.x, zv.x, qx, qy, qz));
    unsigned u1 = __float_as_uint(dist2f(xv.y, yv.y, zv.y, qx, qy, qz));
    unsigned u2 = __float_as_uint(dist2f(xv.z, yv.z, zv.z, qx, qy, qz));
    unsigned u3 = __float_as_uint(dist2f(xv.w, yv.w, zv.w, qx, qy, qz));
    int i0 = i * 4;
    if (u0 < tau) { int p = atomicAdd(&sm.ns, 1); if (p < CAP) { sm.u[p] = u0; sm.idx[p] = i0;     sm.px[p] = xv.x; sm.py[p] = yv.x; sm.pz[p] = zv.x; } }
    if (u1 < tau) { int p = atomicAdd(&sm.ns, 1); if (p < CAP) { sm.u[p] = u1; sm.idx[p] = i0 + 1; sm.px[p] = xv.y; sm.py[p] = yv.y; sm.pz[p] = zv.y; } }
    if (u2 < tau) { int p = atomicAdd(&sm.ns, 1); if (p < CAP) { sm.u[p] = u2; sm.idx[p] = i0 + 2; sm.px[p] = xv.z; sm.py[p] = yv.z; sm.pz[p] = zv.z; } }
    if (u3 < tau) { int p = atomicAdd(&sm.ns, 1); if (p < CAP) { sm.u[p] = u3; sm.idx[p] = i0 + 3; sm.px[p] = xv.w; sm.py[p] = yv.w; sm.pz[p] = zv.w; } }
}

// Exact AoS filter pass. Resets ns; fills u/idx/coords with d^2 < tau.
__device__ void filter_exact(const float4* __restrict__ P4, KSmem& sm, unsigned tau,
                             float qx, float qy, float qz, int tid) {
    if (tid == 0) sm.ns = 0;
    __syncthreads();
#pragma unroll 4
    for (int grp = tid; grp < N_PTS / 4; grp += TPB) {
        float4 f0 = P4[3 * grp + 0];
        float4 f1 = P4[3 * grp + 1];
        float4 f2 = P4[3 * grp + 2];
        float4 xv = make_float4(f0.x, f0.w, f1.z, f2.y);
        float4 yv = make_float4(f0.y, f1.x, f1.w, f2.z);
        float4 zv = make_float4(f0.z, f1.y, f2.x, f2.w);
        push4(sm, xv, yv, zv, grp, tau, qx, qy, qz);
    }
    __syncthreads();
}

// Fallback: histogram-sample tau (round-5 proven). Leaves hist zeroed.
__device__ unsigned sample_tau(const float4* __restrict__ P4, KSmem& sm,
                               float qx, float qy, float qz,
                               int tid, int lane, int wid) {
    for (int j = tid; j < BINS; j += TPB) sm.hist[j] = 0u;
    if (tid == 0) { sm.ns = 0; sm.nd = 0; sm.nt = 0; sm.T = 0u; }
    __syncthreads();
    for (int grp = tid; grp < SAMPLE_GRPS; grp += TPB) {
        float4 f0 = P4[3 * grp + 0];
        float4 f1 = P4[3 * grp + 1];
        float4 f2 = P4[3 * grp + 2];
        atomicAdd(&sm.hist[__float_as_uint(dist2f(f0.x, f0.y, f0.z, qx, qy, qz)) >> SHIFT], 1u);
        atomicAdd(&sm.hist[__float_as_uint(dist2f(f0.w, f1.x, f1.y, qx, qy, qz)) >> SHIFT], 1u);
        atomicAdd(&sm.hist[__float_as_uint(dist2f(f1.z, f1.w, f2.x, qx, qy, qz)) >> SHIFT], 1u);
        atomicAdd(&sm.hist[__float_as_uint(dist2f(f2.y, f2.z, f2.w, qx, qy, qz)) >> SHIFT], 1u);
    }
    __syncthreads();
    unsigned Tc = find_bin(sm, RANK_CUT, tid, lane, wid);
    unsigned tau = (Tc >= BINS - 1) ? 0xFFFFFFFFu : ((Tc + 1) << SHIFT);
    for (int j = tid; j < BINS; j += TPB) sm.hist[j] = 0u;   // re-zero for fine pass
    __syncthreads();
    return tau;
}

// Fallback exact 100-NN (round-5/9/10 proven path).
__device__ void knn_exact(const float4* __restrict__ P4, KSmem& sm,
                          float qx, float qy, float qz,
                          int tid, int lane, int wid, bool save_tau) {
    unsigned tau = sample_tau(P4, sm, qx, qy, qz, tid, lane, wid);
    if (save_tau && tid == 0) sm.tau0 = tau;
    filter_exact(P4, sm, tau, qx, qy, qz, tid);
    fine_select(sm, tau, tid, lane, wid);
}

// int16 2-point filter: low/high shorts of one word per plane. Pushes idx only.
__device__ __forceinline__ void q16filt2(KSmem& sm, unsigned xw, unsigned yw,
                                         unsigned zw, int i0, float tauf,
                                         float Cx, float Cy, float Cz) {
    float dx0 = fmaf((float)(xw & 0xffffu), QS16, Cx);
    float dy0 = fmaf((float)(yw & 0xffffu), QS16, Cy);
    float dz0 = fmaf((float)(zw & 0xffffu), QS16, Cz);
    float d0 = fmaf(dx0, dx0, fmaf(dy0, dy0, dz0 * dz0));
    float dx1 = fmaf((float)(xw >> 16), QS16, Cx);
    float dy1 = fmaf((float)(yw >> 16), QS16, Cy);
    float dz1 = fmaf((float)(zw >> 16), QS16, Cz);
    float d1 = fmaf(dx1, dx1, fmaf(dy1, dy1, dz1 * dz1));
    if (d0 < tauf) { int p = atomicAdd(&sm.ns, 1); if (p < CAP) sm.idx[p] = i0; }
    if (d1 < tauf) { int p = atomicAdd(&sm.ns, 1); if (p < CAP) sm.idx[p] = i0 + 1; }
}

// ---- 3x3 symmetric eigensolve (Jacobi, double) ----
__device__ void eig3(const float cf[6], double lam_out[3], double dir_out[3]) {
    double a[3][3], v[3][3];
    a[0][0] = cf[0]; a[0][1] = cf[1]; a[0][2] = cf[2];
    a[1][0] = cf[1]; a[1][1] = cf[3]; a[1][2] = cf[4];
    a[2][0] = cf[2]; a[2][1] = cf[4]; a[2][2] = cf[5];
    for (int i = 0; i < 3; i++)
        for (int j = 0; j < 3; j++) v[i][j] = (i == j) ? 1.0 : 0.0;
    for (int sweep = 0; sweep < 12; sweep++) {
        double off = a[0][1] * a[0][1] + a[0][2] * a[0][2] + a[1][2] * a[1][2];
        if (off == 0.0) break;
        for (int p = 0; p < 2; p++) {
            for (int q = p + 1; q < 3; q++) {
                double apq = a[p][q];
                if (apq == 0.0) continue;
                double app = a[p][p], aqq = a[q][q];
                double theta = (aqq - app) / (2.0 * apq);
                double t = (theta >= 0.0 ? 1.0 : -1.0) /
                           (fabs(theta) + sqrt(theta * theta + 1.0));
                double c = 1.0 / sqrt(t * t + 1.0);
                double s = t * c;
                a[p][p] = app - t * apq;
                a[q][q] = aqq + t * apq;
                a[p][q] = 0.0; a[q][p] = 0.0;
                for (int r = 0; r < 3; r++) {
                    if (r == p || r == q) continue;
                    double arp = a[r][p], arq = a[r][q];
                    a[r][p] = c * arp - s * arq; a[p][r] = a[r][p];
                    a[r][q] = s * arp + c * arq; a[q][r] = a[r][q];
                }
                for (int r = 0; r < 3; r++) {
                    double vrp = v[r][p], vrq = v[r][q];
                    v[r][p] = c * vrp - s * vrq;
                    v[r][q] = s * vrp + c * vrq;
                }
            }
        }
    }
    double l0 = a[0][0], l1 = a[1][1], l2 = a[2][2];
    int i0 = 0, i1 = 1, i2 = 2;
    if (l0 > l1) { double t = l0; l0 = l1; l1 = t; int ti = i0; i0 = i1; i1 = ti; }
    if (l1 > l2) { double t = l1; l1 = l2; l2 = t; int ti = i1; i1 = i2; i2 = ti; }
    if (l0 > l1) { double t = l0; l0 = l1; l1 = t; int ti = i0; i0 = i1; i1 = ti; }
    lam_out[0] = l0; lam_out[1] = l1; lam_out[2] = l2;
    dir_out[0] = v[0][i2]; dir_out[1] = v[1][i2]; dir_out[2] = v[2][i2];
}

// One block per (batch, group). MODE1 phase 0: register-bisection tau on the
// int16 planes -> int16 filter (half the cache lines of fp32, margin 3e-4)
// -> exact fp32 gather -> exact select + r100<t check. Phase 1: certified
// survivor reuse. Any anomaly -> round-5-proven exact AoS path.
// No mid-kernel cross-block sync; release-only election; ONE acquire in ONE
// block (rounds 2/8 lesson: multi-block acquire = L2 invalidation storm).
template<int MODE>
__global__ __launch_bounds__(TPB)
void fused_knn_kernel(const float* __restrict__ pts,
                      const unsigned short* __restrict__ xq,
                      const unsigned short* __restrict__ yq,
                      const unsigned short* __restrict__ zq,
                      float* __restrict__ gmeans, float* __restrict__ covs,
                      float* __restrict__ out,
                      unsigned* __restrict__ syncw,   // [0]=elect, [1]=OOR flag
                      int B, int nblk) {
    __shared__ KSmem sm;
    __shared__ int s_fastok, s_last, s_exact, s_chk;

    const int blk = blockIdx.x;
    const int b = blk % B;           // batch-per-XCD swizzle (L2 locality)
    const int g = blk / B;
    const int gi = b * G_NUMS + g;   // b-major for finalize
    const float* __restrict__ P = pts + (size_t)b * (N_PTS * 3);
    const float4* __restrict__ P4 = (const float4*)P;
    const unsigned* XW = nullptr; const unsigned* YW = nullptr; const unsigned* ZW = nullptr;
    if (MODE == 1) {
        XW = (const unsigned*)(xq + (size_t)b * N_PTS);
        YW = (const unsigned*)(yq + (size_t)b * N_PTS);
        ZW = (const unsigned*)(zq + (size_t)b * N_PTS);
    }
    const int tid = threadIdx.x;
    const int lane = tid & 63, wid = tid >> 6;

    if (tid == 0) {
        const float* qp = P + (size_t)g * PT_STRIDE * 3;
        sm.q[0] = qp[0]; sm.q[1] = qp[1]; sm.q[2] = qp[2];
        sm.ns = 0; sm.nd = 0; sm.nt = 0; sm.T = 0u;
        s_last = 0;
        s_exact = (MODE == 0) ? 1 : (syncw[1] ? 1 : 0);   // OOR -> exact path
    }
    if (tid < 3) sm.acc[tid] = 0.f;
    if (tid < 6) sm.cov[tid] = 0.f;
    for (int j = tid; j < BINS; j += TPB) sm.hist[j] = 0u;
    __syncthreads();
    const float qx = sm.q[0], qy = sm.q[1], qz = sm.q[2];

    // ================= phase 0 =================
    if (s_exact) {
        knn_exact(P4, sm, qx, qy, qz, tid, lane, wid, true);
    } else {
        // ---- register-bisection tau on quantized sample (all waves identical:
        //      same words, same op order; deterministic; no LDS traffic) ----
        const float Cx = QC16 - qx, Cy = QC16 - qy, Cz = QC16 - qz;
        unsigned tau_q;
        {
            unsigned du[SMP_PL];
#pragma unroll
            for (int k = 0; k < SMP_PL / 2; ++k) {
                int w = lane + 64 * k;              // words 0..1023 = pts 0..2047
                unsigned xw = XW[w], yw = YW[w], zw = ZW[w];
                float dx0 = fmaf((float)(xw & 0xffffu), QS16, Cx);
                float dy0 = fmaf((float)(yw & 0xffffu), QS16, Cy);
                float dz0 = fmaf((float)(zw & 0xffffu), QS16, Cz);
                du[2 * k] = __float_as_uint(fmaf(dx0, dx0, fmaf(dy0, dy0, dz0 * dz0)));
                float dx1 = fmaf((float)(xw >> 16), QS16, Cx);
                float dy1 = fmaf((float)(yw >> 16), QS16, Cy);
                float dz1 = fmaf((float)(zw >> 16), QS16, Cz);
                du[2 * k + 1] = __float_as_uint(fmaf(dx1, dx1, fmaf(dy1, dy1, dz1 * dz1)));
            }
            unsigned lo = 0u, hi = 0x7F800000u;     // count(<lo)<CUT<=count(<hi)
            for (int it = 0; it < SMP_ITERS; ++it) {
                unsigned mid = (lo + hi) >> 1;
                int cnt = 0;
#pragma unroll
                for (int k = 0; k < SMP_PL; ++k) cnt += (du[k] < mid) ? 1 : 0;
#pragma unroll
                for (int off = 1; off < 64; off <<= 1) cnt += __shfl_xor(cnt, off);
                if (cnt >= SMP_CUT) hi = mid; else lo = mid;   // uniform branch
            }
            tau_q = hi;                              // upper bracket (quantized metric)
        }
        const float t = sqrtf(__uint_as_float(tau_q));
        const float tf = t + QM16;
        const float tauf = tf * tf;                  // filter: d_q^2 < tauf
        // exact-d bound on survivors: d_true <= t + 2*QM16
        const float rm = t + 2.0f * QM16;
        const unsigned umax = __float_as_uint(fmaf(rm, rm, 1e-6f) * 1.0001f);
        if (tid == 0) { sm.tau0 = tau_q; sm.ns = 0; }   // cert: non-surv d_true >= t
        __syncthreads();

        // ---- int16 filter: 3 x uint4 = 8 points per unit, 16 units/thread ----
        const uint4* XQ4 = (const uint4*)XW;
        const uint4* YQ4 = (const uint4*)YW;
        const uint4* ZQ4 = (const uint4*)ZW;
#pragma unroll 4
        for (int it = 0; it < N_PTS / 8 / TPB; ++it) {   // 16 iters
            int i = it * TPB + tid;
            uint4 xv = XQ4[i], yv = YQ4[i], zv = ZQ4[i];
            int i0 = i * 8;
            q16filt2(sm, xv.x, yv.x, zv.x, i0 + 0, tauf, Cx, Cy, Cz);
            q16filt2(sm, xv.y, yv.y, zv.y, i0 + 2, tauf, Cx, Cy, Cz);
            q16filt2(sm, xv.z, yv.z, zv.z, i0 + 4, tauf, Cx, Cy, Cz);
            q16filt2(sm, xv.w, yv.w, zv.w, i0 + 6, tauf, Cx, Cy, Cz);
        }
        __syncthreads();
        int S = sm.ns;
        if (S < G_SIZE || S > CAP) {
            knn_exact(P4, sm, qx, qy, qz, tid, lane, wid, true);   // prob ~1e-7
        } else {
            // ---- gather exact coords + exact u for survivors ----
            for (int i = tid; i < S; i += TPB) {
                const float* pp = P + 3 * (size_t)sm.idx[i];
                float x = pp[0], y = pp[1], z = pp[2];
                sm.px[i] = x; sm.py[i] = y; sm.pz[i] = z;
                sm.u[i] = __float_as_uint(dist2f(x, y, z, qx, qy, qz));
            }
            __syncthreads();
            fine_select(sm, umax, tid, lane, wid);
            // verify the true 100th distance lies strictly inside ball(t):
            // survivors contain ALL d_true < t, so r100 < t => exact top-100.
            if (tid == 0) sm.maxu = 0u;
            __syncthreads();
            if (tid < G_SIZE) atomicMax(&sm.maxu, sm.u[sm.sel[tid]]);
            __syncthreads();
            if (tid == 0)
                s_chk = (__uint_as_float(sm.maxu) < t * t * (1.0f - 1e-5f)) ? 1 : 0;
            __syncthreads();
            if (!s_chk) {
                knn_exact(P4, sm, qx, qy, qz, tid, lane, wid, true);
            }
        }
    }

    if (tid < G_SIZE) {
        int p = sm.sel[tid];
        atomicAdd(&sm.acc[0], sm.px[p]);
        atomicAdd(&sm.acc[1], sm.py[p]);
        atomicAdd(&sm.acc[2], sm.pz[p]);
    }
    __syncthreads();
    const int S0 = sm.ns;            // survivor count of the FINAL phase-0 filter
    if (tid == 0) {
        float mx = sm.acc[0] * (1.0f / G_SIZE);
        float my = sm.acc[1] * (1.0f / G_SIZE);
        float mz = sm.acc[2] * (1.0f / G_SIZE);
        gmeans[(size_t)gi * 3 + 0] = mx;
        gmeans[(size_t)gi * 3 + 1] = my;
        gmeans[(size_t)gi * 3 + 2] = mz;
        float dx = mx - qx, dy = my - qy, dz = mz - qz;
        sm.delta2 = fmaf(dx, dx, fmaf(dy, dy, dz * dz));
        sm.q[0] = mx; sm.q[1] = my; sm.q[2] = mz;
        sm.acc[0] = 0.f; sm.acc[1] = 0.f; sm.acc[2] = 0.f;
        sm.maxu = 0u; sm.r1 = 0u; sm.T = 0u;
        sm.nd = 0; sm.nt = 0;
        s_fastok = 0;
    }
    __syncthreads();
    const float q1x = sm.q[0], q1y = sm.q[1], q1z = sm.q[2];

    // ============ phase 1 fast path: certified survivor reuse (LDS coords) ============
    const bool attempt = (S0 >= G_SIZE) && (S0 <= CAP);
    if (attempt) {
        for (int j = tid; j < BINS; j += TPB) sm.hist[j] = 0u;
        for (int i = tid; i < S0; i += TPB) {
            unsigned uu = __float_as_uint(
                dist2f(sm.px[i], sm.py[i], sm.pz[i], q1x, q1y, q1z));
            sm.u[i] = uu;
            atomicMax(&sm.maxu, uu);
        }
        __syncthreads();
        unsigned maxu = sm.maxu;
        unsigned hb = (maxu == 0u) ? 0u : (32u - (unsigned)__clz(maxu));
        unsigned s3 = hb > 12u ? hb - 12u : 0u;
        for (int i = tid; i < S0; i += TPB) atomicAdd(&sm.hist[sm.u[i] >> s3], 1u);
        __syncthreads();
        unsigned T2 = find_bin(sm, G_SIZE, tid, lane, wid);
        const unsigned lo = T2 << s3;
        for (int i = tid; i < S0; i += TPB) {
            unsigned uu = sm.u[i];
            if (uu < lo) {
                int p = atomicAdd(&sm.nd, 1);
                if (p < G_SIZE) sm.sel[p] = i;
            } else if ((uu >> s3) == T2) {
                int p = atomicAdd(&sm.nt, 1);
                if (p < TIE_CAP) { sm.tu[p] = uu; sm.ti[p] = i; }
            }
        }
        __syncthreads();
        if (tid == 0) {
            int ok = 1;
            int nd = sm.nd; if (nd > G_SIZE) { nd = G_SIZE; ok = 0; }
            int need = G_SIZE - nd;
            if (sm.nt > TIE_CAP) ok = 0;
            int ec = sm.nt; if (ec > TIE_CAP) ec = TIE_CAP;
            if (need > ec) ok = 0;
            for (int a = 0; a < need && a < ec; ++a) {
                int best = a;
                for (int j = a + 1; j < ec; ++j)
                    if (sm.tu[j] < sm.tu[best] ||
                        (sm.tu[j] == sm.tu[best] && sm.idx[sm.ti[j]] < sm.idx[sm.ti[best]])) best = j;
                unsigned tub = sm.tu[best]; sm.tu[best] = sm.tu[a]; sm.tu[a] = tub;
                int tib = sm.ti[best]; sm.ti[best] = sm.ti[a]; sm.ti[a] = tib;
                sm.sel[nd + a] = sm.ti[a];
            }
            s_fastok = ok;
        }
        __syncthreads();
        if (s_fastok) {
            if (tid < G_SIZE) atomicMax(&sm.r1, sm.u[sm.sel[tid]]);
            __syncthreads();
            if (tid == 0) {
                // certificate: every non-survivor p has d0(p) >= R0 = sqrt(tau0)
                // (int16 path: filter kept d_q < t+M => non-surv d_true >= t),
                // so d1(p) >= R0 - delta; exact iff R0 - delta > r1 (fp margin)
                double R0 = sqrt((double)__uint_as_float(sm.tau0));
                double dl = sqrt((double)sm.delta2);
                double r1 = sqrt((double)__uint_as_float(sm.r1));
                if (!((R0 - dl) > r1 * 1.0001 + 1e-7)) s_fastok = 0;
            }
            __syncthreads();
        }
    }

    // ============ phase 1 fallback: exact full scan (rare) ============
    if (!attempt || !s_fastok) {
        knn_exact(P4, sm, q1x, q1y, q1z, tid, lane, wid, false);
    }

    // ============ mean / covariance over the exact 100 (LDS coords) ============
    float px = 0.f, py = 0.f, pz = 0.f;
    if (tid < G_SIZE) {
        int p = sm.sel[tid];
        px = sm.px[p]; py = sm.py[p]; pz = sm.pz[p];
        atomicAdd(&sm.acc[0], px);
        atomicAdd(&sm.acc[1], py);
        atomicAdd(&sm.acc[2], pz);
    }
    __syncthreads();
    float mx = sm.acc[0] * (1.0f / G_SIZE);
    float my = sm.acc[1] * (1.0f / G_SIZE);
    float mz = sm.acc[2] * (1.0f / G_SIZE);
    if (tid < G_SIZE) {
        float x = px - mx, y = py - my, z = pz - mz;
        atomicAdd(&sm.cov[0], x * x);
        atomicAdd(&sm.cov[1], x * y);
        atomicAdd(&sm.cov[2], x * z);
        atomicAdd(&sm.cov[3], y * y);
        atomicAdd(&sm.cov[4], y * z);
        atomicAdd(&sm.cov[5], z * z);
    }
    __syncthreads();
    if (tid < 6) covs[(size_t)gi * 6 + tid] = sm.cov[tid] * (1.0f / G_SIZE);

    // ============ last-block election (release-only; after ALL heavy work) ============
    __syncthreads();
    if (tid == 0) {
        unsigned old = __hip_atomic_fetch_add(&syncw[0], 1u, __ATOMIC_RELEASE,
                                              __HIP_MEMORY_SCOPE_AGENT);
        s_last = (old == (unsigned)(nblk - 1)) ? 1 : 0;
    }
    __syncthreads();
    if (!s_last) return;

    // ============ finalize (runs once, in the last block) ============
    // single acquire (one L2 invalidate, one block) to see all blocks' outputs
    (void)__hip_atomic_load(&syncw[0], __ATOMIC_ACQUIRE, __HIP_MEMORY_SCOPE_AGENT);
    const int NG = nblk;             // 240
    float et = 0.f;
    if (tid < NG) {
        float cf[6];
#pragma unroll
        for (int j = 0; j < 6; j++) cf[j] = covs[tid * 6 + j];
        double lam[3], dir[3];
        eig3(cf, lam, dir);
        double denom = lam[0] + lam[1] + lam[2] + 1e-9;
        et = (float)((lam[2] - lam[1]) / denom);
        sm.fin.dir[tid][0] = (float)dir[0];
        sm.fin.dir[tid][1] = (float)dir[1];
        sm.fin.dir[tid][2] = (float)dir[2];
        sm.fin.gm[tid][0] = gmeans[tid * 3 + 0];
        sm.fin.gm[tid][1] = gmeans[tid * 3 + 1];
        sm.fin.gm[tid][2] = gmeans[tid * 3 + 2];
    }
    __syncthreads();

    float st = 0.f;
    if (tid < NG) {
        int bb = tid / G_NUMS, gg0 = tid % G_NUMS;
        float gx = sm.fin.gm[tid][0], gy = sm.fin.gm[tid][1], gz = sm.fin.gm[tid][2];
        float bd = 3.4e38f; int bj = 0;
        for (int gg = 0; gg < G_NUMS; gg++) {
            if (gg == gg0) continue;
            int o = bb * G_NUMS + gg;
            float dx = gx - sm.fin.gm[o][0];
            float dy = gy - sm.fin.gm[o][1];
            float dz = gz - sm.fin.gm[o][2];
            float d = dx * dx + dy * dy + dz * dz;
            if (d < bd) { bd = d; bj = gg; }
        }
        int o = bb * G_NUMS + bj;
        float cosv = sm.fin.dir[tid][0] * sm.fin.dir[o][0] +
                     sm.fin.dir[tid][1] * sm.fin.dir[o][1] +
                     sm.fin.dir[tid][2] * sm.fin.dir[o][2];
        st = 1.f - cosv * cosv;
    }

    float e = et, s2v = st;
#pragma unroll
    for (int off = 32; off > 0; off >>= 1) {
        e += __shfl_down(e, off);
        s2v += __shfl_down(s2v, off);
    }
    if (lane == 0) { sm.fin.pe[wid] = e; sm.fin.ps[wid] = s2v; }
    __syncthreads();
    if (tid == 0) {
        float se = 0.f, ss = 0.f;
        for (int w = 0; w < NWAVES; w++) { se += sm.fin.pe[w]; ss += sm.fin.ps[w]; }
        out[0] = -se / (float)B + ss / (float)NG;
    }
}

// AoS -> int16 SoA planes. Sets OOR flag (syncw[1]) if any coord leaves [-8,8).
__global__ __launch_bounds__(256)
void quant16_kernel(const float* __restrict__ pts,
                    unsigned short* __restrict__ xq, unsigned short* __restrict__ yq,
                    unsigned short* __restrict__ zq, unsigned* __restrict__ syncw,
                    int total4) {
    int t = blockIdx.x * 256 + threadIdx.x;
    if (t >= total4) return;
    const float4* __restrict__ P4 = (const float4*)pts;
    float4 f0 = P4[3 * t + 0];
    float4 f1 = P4[3 * t + 1];
    float4 f2 = P4[3 * t + 2];
    float xs[4] = {f0.x, f0.w, f1.z, f2.y};
    float ys[4] = {f0.y, f1.x, f1.w, f2.z};
    float zs[4] = {f0.z, f1.y, f2.x, f2.w};
    unsigned xw[2] = {0, 0}, yw[2] = {0, 0}, zw[2] = {0, 0};
    int bad = 0;
#pragma unroll
    for (int j = 0; j < 4; ++j) {
        int ix = (int)floorf((xs[j] + 8.0f) * 4096.0f);
        int iy = (int)floorf((ys[j] + 8.0f) * 4096.0f);
        int iz = (int)floorf((zs[j] + 8.0f) * 4096.0f);
        if ((unsigned)ix > 65535u || (unsigned)iy > 65535u || (unsigned)iz > 65535u) bad = 1;
        ix = ix < 0 ? 0 : (ix > 65535 ? 65535 : ix);
        iy = iy < 0 ? 0 : (iy > 65535 ? 65535 : iy);
        iz = iz < 0 ? 0 : (iz > 65535 ? 65535 : iz);
        xw[j >> 1] |= (unsigned)ix << (16 * (j & 1));
        yw[j >> 1] |= (unsigned)iy << (16 * (j & 1));
        zw[j >> 1] |= (unsigned)iz << (16 * (j & 1));
    }
    ((uint2*)xq)[t] = make_uint2(xw[0], xw[1]);
    ((uint2*)yq)[t] = make_uint2(yw[0], yw[1]);
    ((uint2*)zq)[t] = make_uint2(zw[0], zw[1]);
    if (bad) atomicOr(&syncw[1], 1u);
}

extern "C" void kernel_launch(void* const* d_in, const int* in_sizes, int n_in,
                              void* d_out, int out_size, void* d_ws, size_t ws_size,
                              hipStream_t stream) {
    const float* pts = (const float*)d_in[0];
    float* out = (float*)d_out;
    float* ws = (float*)d_ws;
    int B = in_sizes[0] / (N_PTS * 3);   // 8
    int nblk = B * G_NUMS;               // 240

    float* gmeans = ws;                                  // 3*nblk floats
    float* covs = ws + (size_t)3 * nblk;                 // 6*nblk floats
    unsigned* syncw = (unsigned*)(ws + (size_t)9 * nblk);   // 16 u32
    size_t plane_off = ((size_t)9 * nblk + 16) * 4;         // bytes
    plane_off = (plane_off + 15) & ~(size_t)15;             // 16B align
    unsigned short* xqp = (unsigned short*)((char*)d_ws + plane_off);
    size_t planeB = (size_t)B * N_PTS * 2;                  // 2 MB per plane
    unsigned short* yqp = (unsigned short*)((char*)xqp + planeB);
    unsigned short* zqp = (unsigned short*)((char*)yqp + planeB);
    size_t need = plane_off + 3 * planeB;
    const int use_q = ws_size >= need;

    hipMemsetAsync(syncw, 0, 64, stream);    // zero elect + OOR flag

    dim3 grid(nblk);
    if (use_q) {
        int total4 = B * N_PTS / 4;
        quant16_kernel<<<dim3((total4 + 255) / 256), dim3(256), 0, stream>>>(
            pts, xqp, yqp, zqp, syncw, total4);
        fused_knn_kernel<1><<<grid, dim3(TPB), 0, stream>>>(
            pts, xqp, yqp, zqp, gmeans, covs, out, syncw, B, nblk);
    } else {
        fused_knn_kernel<0><<<grid, dim3(TPB), 0, stream>>>(
            pts, nullptr, nullptr, nullptr, gmeans, covs, out, syncw, B, nblk);
    }
}

// Round 12
// 137.172 us; speedup vs baseline: 1.1019x; 1.1019x over previous
//
#include <hip/hip_runtime.h>
#include <math.h>

#define N_PTS     131072
#define G_NUMS    30
#define G_SIZE    100
#define PT_STRIDE (N_PTS / G_NUMS)   // 4369
#define TPB       1024
#define NWAVES    (TPB / 64)         // 16
#define BINS      4096
#define JB        (BINS / TPB)       // 4 bins per thread
#define SHIFT     20
#define SAMPLE_GRPS 1024             // first 4096 points as iid sample
#define RANK_CUT  32                 // 32nd-smallest sample -> tau (P(fail) ~ 1e-7/block)
#define CAP       3072               // survivor capacity
#define TIE_CAP   64
// int8 quantization: [-8,8) in 256 steps
#define QS        0.0625f            // step
#define QOFF      (-8.0f + 0.03125f) // bin-center reconstruction offset
#define QMARGIN   0.0542f            // sqrt(3)*step/2, rounded up

typedef unsigned char uchar_t;

struct KSmem {
    union {
        unsigned hist[BINS];         // 16 KB
        struct {                     // finalize overlay (last block only)
            float gm[256][3];
            float dir[256][3];
            float pe[NWAVES];
            float ps[NWAVES];
        } fin;
    };
    unsigned wsum[NWAVES];
    unsigned T;
    int ns, nd, nt;
    unsigned u[CAP];
    int idx[CAP];
    float px[CAP], py[CAP], pz[CAP]; // survivor coords (exact fp32) in LDS
    int sel[G_SIZE];                 // positions into survivor arrays
    unsigned tu[TIE_CAP];
    int ti[TIE_CAP];                 // positions
    float acc[3], cov[6], q[3];
    unsigned tau0, maxu, r1;
    float delta2;
};

__device__ __forceinline__ float dist2f(float px, float py, float pz,
                                        float qx, float qy, float qz) {
    float dx = px - qx, dy = py - qy, dz = pz - qz;
    return fmaf(dx, dx, fmaf(dy, dy, dz * dz));
}

// Find smallest bin T such that cumulative count through T >= rank.
__device__ __forceinline__ unsigned find_bin(KSmem& sm, unsigned rank,
                                             int tid, int lane, int wid) {
    unsigned hv[JB], csum = 0;
#pragma unroll
    for (int j = 0; j < JB; j++) { hv[j] = sm.hist[tid * JB + j]; csum += hv[j]; }
    unsigned inc = csum;
#pragma unroll
    for (int off = 1; off < 64; off <<= 1) {
        unsigned n = __shfl_up(inc, off);
        if (lane >= off) inc += n;
    }
    __syncthreads();                  // protect wsum reuse across calls
    if (lane == 63) sm.wsum[wid] = inc;
    __syncthreads();
    unsigned base = 0;
    for (int w = 0; w < wid; w++) base += sm.wsum[w];
    unsigned c = base + inc - csum;   // exclusive prefix before this thread's chunk
#pragma unroll
    for (int j = 0; j < JB; j++) {
        if (c < rank && c + hv[j] >= rank) sm.T = (unsigned)(tid * JB + j);
        c += hv[j];
    }
    __syncthreads();
    return sm.T;
}

// Exact top-100 select over sm.u[0..min(ns,CAP)) -> sm.sel positions.
// ubound: known upper bound (bits) on all u values (sets histogram shift).
// Requires sm.hist zeroed and sm.nd/nt zeroed on entry.
__device__ void fine_select(KSmem& sm, unsigned ubound, int tid, int lane, int wid) {
    int S = sm.ns; if (S > CAP) S = CAP;
    unsigned hb = 32u - (unsigned)__clz(ubound | 1u);
    unsigned s2 = hb > 12u ? hb - 12u : 0u;
    for (int i = tid; i < S; i += TPB) {
        unsigned bin = sm.u[i] >> s2; if (bin > BINS - 1u) bin = BINS - 1u;
        atomicAdd(&sm.hist[bin], 1u);
    }
    __syncthreads();
    unsigned T2 = find_bin(sm, G_SIZE, tid, lane, wid);
    for (int i = tid; i < S; i += TPB) {
        unsigned uu = sm.u[i];
        unsigned bin = uu >> s2; if (bin > BINS - 1u) bin = BINS - 1u;
        if (bin < T2) {
            int p = atomicAdd(&sm.nd, 1);
            if (p < G_SIZE) sm.sel[p] = i;
        } else if (bin == T2) {
            int p = atomicAdd(&sm.nt, 1);
            if (p < TIE_CAP) { sm.tu[p] = uu; sm.ti[p] = i; }
        }
    }
    __syncthreads();
    if (tid == 0) {
        int nd = sm.nd; if (nd > G_SIZE) nd = G_SIZE;
        int need = G_SIZE - nd;
        int ec = sm.nt; if (ec > TIE_CAP) ec = TIE_CAP;
        for (int a = 0; a < need && a < ec; ++a) {
            int best = a;
            for (int j = a + 1; j < ec; ++j)
                if (sm.tu[j] < sm.tu[best] ||
                    (sm.tu[j] == sm.tu[best] && sm.idx[sm.ti[j]] < sm.idx[sm.ti[best]])) best = j;
            unsigned tub = sm.tu[best]; sm.tu[best] = sm.tu[a]; sm.tu[a] = tub;
            int tib = sm.ti[best]; sm.ti[best] = sm.ti[a]; sm.ti[a] = tib;
            sm.sel[nd + a] = sm.ti[a];
        }
    }
    __syncthreads();
}

// Exact AoS distance+filter+stash for one float4-group (4 points).
__device__ __forceinline__ void push4(KSmem& sm, const float4& xv, const float4& yv,
                                      const float4& zv, int i, unsigned tau,
                                      float qx, float qy, float qz) {
    unsigned u0 = __float_as_uint(dist2f(xv.x, yv.x, zv.x, qx, qy, qz));
    unsigned u1 = __float_as_uint(dist2f(xv.y, yv.y, zv.y, qx, qy, qz));
    unsigned u2 = __float_as_uint(dist2f(xv.z, yv.z, zv.z, qx, qy, qz));
    unsigned u3 = __float_as_uint(dist2f(xv.w, yv.w, zv.w, qx, qy, qz));
    int i0 = i * 4;
    if (u0 < tau) { int p = atomicAdd(&sm.ns, 1); if (p < CAP) { sm.u[p] = u0; sm.idx[p] = i0;     sm.px[p] = xv.x; sm.py[p] = yv.x; sm.pz[p] = zv.x; } }
    if (u1 < tau) { int p = atomicAdd(&sm.ns, 1); if (p < CAP) { sm.u[p] = u1; sm.idx[p] = i0 + 1; sm.px[p] = xv.y; sm.py[p] = yv.y; sm.pz[p] = zv.y; } }
    if (u2 < tau) { int p = atomicAdd(&sm.ns, 1); if (p < CAP) { sm.u[p] = u2; sm.idx[p] = i0 + 2; sm.px[p] = xv.z; sm.py[p] = yv.z; sm.pz[p] = zv.z; } }
    if (u3 < tau) { int p = atomicAdd(&sm.ns, 1); if (p < CAP) { sm.u[p] = u3; sm.idx[p] = i0 + 3; sm.px[p] = xv.w; sm.py[p] = yv.w; sm.pz[p] = zv.w; } }
}

// Exact AoS filter pass (no histogram use). Resets ns; fills u/idx/coords.
__device__ void filter_exact(const float4* __restrict__ P4, KSmem& sm, unsigned tau,
                             float qx, float qy, float qz, int tid) {
    if (tid == 0) sm.ns = 0;
    __syncthreads();
#pragma unroll 4
    for (int grp = tid; grp < N_PTS / 4; grp += TPB) {
        float4 f0 = P4[3 * grp + 0];
        float4 f1 = P4[3 * grp + 1];
        float4 f2 = P4[3 * grp + 2];
        float4 xv = make_float4(f0.x, f0.w, f1.z, f2.y);
        float4 yv = make_float4(f0.y, f1.x, f1.w, f2.z);
        float4 zv = make_float4(f0.z, f1.y, f2.x, f2.w);
        push4(sm, xv, yv, zv, grp, tau, qx, qy, qz);
    }
    __syncthreads();
}

// Sample (exact AoS) -> tau. Leaves hist zeroed for the fine select.
__device__ unsigned sample_tau(const float4* __restrict__ P4, KSmem& sm,
                               float qx, float qy, float qz,
                               int tid, int lane, int wid) {
    for (int j = tid; j < BINS; j += TPB) sm.hist[j] = 0u;
    if (tid == 0) { sm.ns = 0; sm.nd = 0; sm.nt = 0; sm.T = 0u; }
    __syncthreads();
    for (int grp = tid; grp < SAMPLE_GRPS; grp += TPB) {
        float4 f0 = P4[3 * grp + 0];
        float4 f1 = P4[3 * grp + 1];
        float4 f2 = P4[3 * grp + 2];
        atomicAdd(&sm.hist[__float_as_uint(dist2f(f0.x, f0.y, f0.z, qx, qy, qz)) >> SHIFT], 1u);
        atomicAdd(&sm.hist[__float_as_uint(dist2f(f0.w, f1.x, f1.y, qx, qy, qz)) >> SHIFT], 1u);
        atomicAdd(&sm.hist[__float_as_uint(dist2f(f1.z, f1.w, f2.x, qx, qy, qz)) >> SHIFT], 1u);
        atomicAdd(&sm.hist[__float_as_uint(dist2f(f2.y, f2.z, f2.w, qx, qy, qz)) >> SHIFT], 1u);
    }
    __syncthreads();
    unsigned Tc = find_bin(sm, RANK_CUT, tid, lane, wid);
    unsigned tau = (Tc >= BINS - 1) ? 0xFFFFFFFFu : ((Tc + 1) << SHIFT);
    for (int j = tid; j < BINS; j += TPB) sm.hist[j] = 0u;   // re-zero for fine pass
    __syncthreads();
    return tau;
}

// Exact 100-NN, fully exact AoS path (round-5 proven).
__device__ void knn_exact(const float4* __restrict__ P4, KSmem& sm,
                          float qx, float qy, float qz,
                          int tid, int lane, int wid, bool save_tau) {
    unsigned tau = sample_tau(P4, sm, qx, qy, qz, tid, lane, wid);
    if (save_tau && tid == 0) sm.tau0 = tau;
    filter_exact(P4, sm, tau, qx, qy, qz, tid);
    fine_select(sm, tau, tid, lane, wid);
}

// int8 4-point filter: bytes of one word per plane.
__device__ __forceinline__ void q8filt4(KSmem& sm, unsigned xw, unsigned yw,
                                        unsigned zw, int i0, float tauf,
                                        float Cx, float Cy, float Cz) {
#pragma unroll
    for (int j = 0; j < 4; ++j) {
        float dx = fmaf((float)((xw >> (8 * j)) & 0xffu), QS, Cx);
        float dy = fmaf((float)((yw >> (8 * j)) & 0xffu), QS, Cy);
        float dz = fmaf((float)((zw >> (8 * j)) & 0xffu), QS, Cz);
        float d2 = fmaf(dx, dx, fmaf(dy, dy, dz * dz));
        if (d2 < tauf) {
            int p = atomicAdd(&sm.ns, 1);
            if (p < CAP) sm.idx[p] = i0 + j;
        }
    }
}

// Exact 100-NN via int8-quantized filter + exact gather. Certificate-safe:
// filter keeps all d_true < sqrt(tau) (margin QMARGIN); non-survivors have
// d_true >= sqrt(tau), so R0 = sqrt(tau0) stays valid for phase 1.
__device__ void knn_q8(const float* __restrict__ P, const float4* __restrict__ P4,
                       const uint4* __restrict__ XQ, const uint4* __restrict__ YQ,
                       const uint4* __restrict__ ZQ, KSmem& sm,
                       float qx, float qy, float qz, int tid, int lane, int wid) {
    unsigned tau = sample_tau(P4, sm, qx, qy, qz, tid, lane, wid);
    if (tid == 0) { sm.tau0 = tau; sm.ns = 0; }
    __syncthreads();
    const bool bad_tau = (tau >= 0x7F800000u);   // degenerate: go exact
    float tauf = 0.f; unsigned umax = 0u;
    if (!bad_tau) {
        float rt = sqrtf(__uint_as_float(tau)) + QMARGIN;
        tauf = rt * rt;                           // inflated filter threshold
        float rm = sqrtf(tauf) + QMARGIN;         // bound on exact d of survivors
        umax = __float_as_uint(fmaf(rm, rm, 1e-6f) * 1.0001f);

        // ---- int8 filter: 3 x uint4 per iter = 16 points/thread/iter ----
        const float Cx = QOFF - qx, Cy = QOFF - qy, Cz = QOFF - qz;
#pragma unroll 2
        for (int it = 0; it < N_PTS / 16 / TPB; ++it) {   // 8 iters
            int i = it * TPB + tid;
            uint4 xv = XQ[i], yv = YQ[i], zv = ZQ[i];
            int i0 = i * 16;
            q8filt4(sm, xv.x, yv.x, zv.x, i0 + 0,  tauf, Cx, Cy, Cz);
            q8filt4(sm, xv.y, yv.y, zv.y, i0 + 4,  tauf, Cx, Cy, Cz);
            q8filt4(sm, xv.z, yv.z, zv.z, i0 + 8,  tauf, Cx, Cy, Cz);
            q8filt4(sm, xv.w, yv.w, zv.w, i0 + 12, tauf, Cx, Cy, Cz);
        }
        __syncthreads();
    }
    int S = sm.ns;
    if (bad_tau || S > CAP) {
        // overflow or degenerate tau: exact refilter (survivors = u < tau)
        filter_exact(P4, sm, tau, qx, qy, qz, tid);
        fine_select(sm, tau, tid, lane, wid);
        return;
    }
    // ---- gather exact coords + exact u for survivors ----
    for (int i = tid; i < S; i += TPB) {
        const float* pp = P + 3 * (size_t)sm.idx[i];
        float x = pp[0], y = pp[1], z = pp[2];
        sm.px[i] = x; sm.py[i] = y; sm.pz[i] = z;
        sm.u[i] = __float_as_uint(dist2f(x, y, z, qx, qy, qz));
    }
    __syncthreads();
    fine_select(sm, umax, tid, lane, wid);
}

// ---- 3x3 symmetric eigensolve (Jacobi, double) ----
__device__ void eig3(const float cf[6], double lam_out[3], double dir_out[3]) {
    double a[3][3], v[3][3];
    a[0][0] = cf[0]; a[0][1] = cf[1]; a[0][2] = cf[2];
    a[1][0] = cf[1]; a[1][1] = cf[3]; a[1][2] = cf[4];
    a[2][0] = cf[2]; a[2][1] = cf[4]; a[2][2] = cf[5];
    for (int i = 0; i < 3; i++)
        for (int j = 0; j < 3; j++) v[i][j] = (i == j) ? 1.0 : 0.0;
    for (int sweep = 0; sweep < 12; sweep++) {
        double off = a[0][1] * a[0][1] + a[0][2] * a[0][2] + a[1][2] * a[1][2];
        if (off == 0.0) break;
        for (int p = 0; p < 2; p++) {
            for (int q = p + 1; q < 3; q++) {
                double apq = a[p][q];
                if (apq == 0.0) continue;
                double app = a[p][p], aqq = a[q][q];
                double theta = (aqq - app) / (2.0 * apq);
                double t = (theta >= 0.0 ? 1.0 : -1.0) /
                           (fabs(theta) + sqrt(theta * theta + 1.0));
                double c = 1.0 / sqrt(t * t + 1.0);
                double s = t * c;
                a[p][p] = app - t * apq;
                a[q][q] = aqq + t * apq;
                a[p][q] = 0.0; a[q][p] = 0.0;
                for (int r = 0; r < 3; r++) {
                    if (r == p || r == q) continue;
                    double arp = a[r][p], arq = a[r][q];
                    a[r][p] = c * arp - s * arq; a[p][r] = a[r][p];
                    a[r][q] = s * arp + c * arq; a[q][r] = a[r][q];
                }
                for (int r = 0; r < 3; r++) {
                    double vrp = v[r][p], vrq = v[r][q];
                    v[r][p] = c * vrp - s * vrq;
                    v[r][q] = s * vrp + c * vrq;
                }
            }
        }
    }
    double l0 = a[0][0], l1 = a[1][1], l2 = a[2][2];
    int i0 = 0, i1 = 1, i2 = 2;
    if (l0 > l1) { double t = l0; l0 = l1; l1 = t; int ti = i0; i0 = i1; i1 = ti; }
    if (l1 > l2) { double t = l1; l1 = l2; l2 = t; int ti = i1; i1 = i2; i2 = ti; }
    if (l0 > l1) { double t = l0; l0 = l1; l1 = t; int ti = i0; i0 = i1; i1 = ti; }
    lam_out[0] = l0; lam_out[1] = l1; lam_out[2] = l2;
    dir_out[0] = v[0][i2]; dir_out[1] = v[1][i2]; dir_out[2] = v[2][i2];
}

// One block per (batch, group). Round-5 proven structure. MODE1 adds the
// int8-quantized filter (exact result via exact-gather + certificate).
// No mid-kernel cross-block sync; single release-only election at the end;
// ONE acquire in ONE block (rounds 2/8 lesson: >1 acquire = L2 invalidation storm).
template<int MODE>
__global__ __launch_bounds__(TPB)
void fused_knn_kernel(const float* __restrict__ pts,
                      const uchar_t* __restrict__ xq, const uchar_t* __restrict__ yq,
                      const uchar_t* __restrict__ zq,
                      float* __restrict__ gmeans, float* __restrict__ covs,
                      float* __restrict__ out,
                      unsigned* __restrict__ syncw,   // [0]=elect, [1]=OOR flag
                      int B, int nblk) {
    __shared__ KSmem sm;
    __shared__ int s_fastok;
    __shared__ int s_last;
    __shared__ int s_exact;

    const int blk = blockIdx.x;
    const int b = blk % B;           // batch-per-XCD swizzle (L2 locality)
    const int g = blk / B;
    const int gi = b * G_NUMS + g;   // b-major for finalize
    const float* __restrict__ P = pts + (size_t)b * (N_PTS * 3);
    const float4* __restrict__ P4 = (const float4*)P;
    const uint4* XQ = nullptr; const uint4* YQ = nullptr; const uint4* ZQ = nullptr;
    if (MODE == 1) {
        XQ = (const uint4*)(xq + (size_t)b * N_PTS);
        YQ = (const uint4*)(yq + (size_t)b * N_PTS);
        ZQ = (const uint4*)(zq + (size_t)b * N_PTS);
    }
    const int tid = threadIdx.x;
    const int lane = tid & 63, wid = tid >> 6;

    if (tid == 0) {
        const float* qp = P + (size_t)g * PT_STRIDE * 3;
        sm.q[0] = qp[0]; sm.q[1] = qp[1]; sm.q[2] = qp[2];
        s_exact = (MODE == 0) ? 1 : (syncw[1] ? 1 : 0);   // OOR -> exact path
    }
    if (tid < 3) sm.acc[tid] = 0.f;
    if (tid < 6) sm.cov[tid] = 0.f;
    __syncthreads();
    const float qx = sm.q[0], qy = sm.q[1], qz = sm.q[2];

    // ================= phase 0 =================
    if (s_exact) knn_exact(P4, sm, qx, qy, qz, tid, lane, wid, true);
    else         knn_q8(P, P4, XQ, YQ, ZQ, sm, qx, qy, qz, tid, lane, wid);

    if (tid < G_SIZE) {
        int p = sm.sel[tid];
        atomicAdd(&sm.acc[0], sm.px[p]);
        atomicAdd(&sm.acc[1], sm.py[p]);
        atomicAdd(&sm.acc[2], sm.pz[p]);
    }
    __syncthreads();
    const int S0 = sm.ns;            // raw phase-0 survivor count
    if (tid == 0) {
        float mx = sm.acc[0] * (1.0f / G_SIZE);
        float my = sm.acc[1] * (1.0f / G_SIZE);
        float mz = sm.acc[2] * (1.0f / G_SIZE);
        gmeans[(size_t)gi * 3 + 0] = mx;
        gmeans[(size_t)gi * 3 + 1] = my;
        gmeans[(size_t)gi * 3 + 2] = mz;
        float dx = mx - qx, dy = my - qy, dz = mz - qz;
        sm.delta2 = fmaf(dx, dx, fmaf(dy, dy, dz * dz));
        sm.q[0] = mx; sm.q[1] = my; sm.q[2] = mz;
        sm.acc[0] = 0.f; sm.acc[1] = 0.f; sm.acc[2] = 0.f;
        sm.maxu = 0u; sm.r1 = 0u; sm.T = 0u;
        sm.nd = 0; sm.nt = 0;
        s_last = 0;
        s_fastok = 0;
    }
    __syncthreads();
    const float q1x = sm.q[0], q1y = sm.q[1], q1z = sm.q[2];

    // ============ phase 1 fast path: certified survivor reuse (LDS coords) ============
    const bool attempt = (S0 >= G_SIZE) && (S0 <= CAP);  // complete survivor set
    if (attempt) {
        for (int j = tid; j < BINS; j += TPB) sm.hist[j] = 0u;
        for (int i = tid; i < S0; i += TPB) {
            unsigned uu = __float_as_uint(
                dist2f(sm.px[i], sm.py[i], sm.pz[i], q1x, q1y, q1z));
            sm.u[i] = uu;
            atomicMax(&sm.maxu, uu);
        }
        __syncthreads();
        unsigned maxu = sm.maxu;
        unsigned hb = (maxu == 0u) ? 0u : (32u - (unsigned)__clz(maxu));
        unsigned s3 = hb > 12u ? hb - 12u : 0u;
        for (int i = tid; i < S0; i += TPB) atomicAdd(&sm.hist[sm.u[i] >> s3], 1u);
        __syncthreads();
        unsigned T2 = find_bin(sm, G_SIZE, tid, lane, wid);
        const unsigned lo = T2 << s3;
        for (int i = tid; i < S0; i += TPB) {
            unsigned uu = sm.u[i];
            if (uu < lo) {
                int p = atomicAdd(&sm.nd, 1);
                if (p < G_SIZE) sm.sel[p] = i;
            } else if ((uu >> s3) == T2) {
                int p = atomicAdd(&sm.nt, 1);
                if (p < TIE_CAP) { sm.tu[p] = uu; sm.ti[p] = i; }
            }
        }
        __syncthreads();
        if (tid == 0) {
            int ok = 1;
            int nd = sm.nd; if (nd > G_SIZE) { nd = G_SIZE; ok = 0; }
            int need = G_SIZE - nd;
            if (sm.nt > TIE_CAP) ok = 0;
            int ec = sm.nt; if (ec > TIE_CAP) ec = TIE_CAP;
            if (need > ec) ok = 0;
            for (int a = 0; a < need && a < ec; ++a) {
                int best = a;
                for (int j = a + 1; j < ec; ++j)
                    if (sm.tu[j] < sm.tu[best] ||
                        (sm.tu[j] == sm.tu[best] && sm.idx[sm.ti[j]] < sm.idx[sm.ti[best]])) best = j;
                unsigned tub = sm.tu[best]; sm.tu[best] = sm.tu[a]; sm.tu[a] = tub;
                int tib = sm.ti[best]; sm.ti[best] = sm.ti[a]; sm.ti[a] = tib;
                sm.sel[nd + a] = sm.ti[a];
            }
            s_fastok = ok;
        }
        __syncthreads();
        if (s_fastok) {
            if (tid < G_SIZE) atomicMax(&sm.r1, sm.u[sm.sel[tid]]);
            __syncthreads();
            if (tid == 0) {
                // certificate: every non-survivor p has d0(p) >= R0 = sqrt(tau0)
                // (holds for int8 path too: margin construction), so
                // d1(p) >= R0 - delta; exact iff R0 - delta > r1 (fp margin)
                double R0 = sqrt((double)__uint_as_float(sm.tau0));
                double dl = sqrt((double)sm.delta2);
                double r1 = sqrt((double)__uint_as_float(sm.r1));
                if (!((R0 - dl) > r1 * 1.0001 + 1e-7)) s_fastok = 0;
            }
            __syncthreads();
        }
    }

    // ============ phase 1 fallback: exact full scan (rare) ============
    if (!attempt || !s_fastok) {
        knn_exact(P4, sm, q1x, q1y, q1z, tid, lane, wid, false);
    }

    // ============ mean / covariance over the exact 100 (LDS coords) ============
    float px = 0.f, py = 0.f, pz = 0.f;
    if (tid < G_SIZE) {
        int p = sm.sel[tid];
        px = sm.px[p]; py = sm.py[p]; pz = sm.pz[p];
        atomicAdd(&sm.acc[0], px);
        atomicAdd(&sm.acc[1], py);
        atomicAdd(&sm.acc[2], pz);
    }
    __syncthreads();
    float mx = sm.acc[0] * (1.0f / G_SIZE);
    float my = sm.acc[1] * (1.0f / G_SIZE);
    float mz = sm.acc[2] * (1.0f / G_SIZE);
    if (tid < G_SIZE) {
        float x = px - mx, y = py - my, z = pz - mz;
        atomicAdd(&sm.cov[0], x * x);
        atomicAdd(&sm.cov[1], x * y);
        atomicAdd(&sm.cov[2], x * z);
        atomicAdd(&sm.cov[3], y * y);
        atomicAdd(&sm.cov[4], y * z);
        atomicAdd(&sm.cov[5], z * z);
    }
    __syncthreads();
    if (tid < 6) covs[(size_t)gi * 6 + tid] = sm.cov[tid] * (1.0f / G_SIZE);

    // ============ last-block election (release-only; after ALL heavy work) ============
    __syncthreads();
    if (tid == 0) {
        unsigned old = __hip_atomic_fetch_add(&syncw[0], 1u, __ATOMIC_RELEASE,
                                              __HIP_MEMORY_SCOPE_AGENT);
        s_last = (old == (unsigned)(nblk - 1)) ? 1 : 0;
    }
    __syncthreads();
    if (!s_last) return;

    // ============ finalize (runs once, in the last block) ============
    // single acquire (one L2 invalidate, one block) to see all blocks' outputs
    (void)__hip_atomic_load(&syncw[0], __ATOMIC_ACQUIRE, __HIP_MEMORY_SCOPE_AGENT);
    const int NG = nblk;             // 240
    float et = 0.f;
    if (tid < NG) {
        float cf[6];
#pragma unroll
        for (int j = 0; j < 6; j++) cf[j] = covs[tid * 6 + j];
        double lam[3], dir[3];
        eig3(cf, lam, dir);
        double denom = lam[0] + lam[1] + lam[2] + 1e-9;
        et = (float)((lam[2] - lam[1]) / denom);
        sm.fin.dir[tid][0] = (float)dir[0];
        sm.fin.dir[tid][1] = (float)dir[1];
        sm.fin.dir[tid][2] = (float)dir[2];
        sm.fin.gm[tid][0] = gmeans[tid * 3 + 0];
        sm.fin.gm[tid][1] = gmeans[tid * 3 + 1];
        sm.fin.gm[tid][2] = gmeans[tid * 3 + 2];
    }
    __syncthreads();

    float st = 0.f;
    if (tid < NG) {
        int bb = tid / G_NUMS, gg0 = tid % G_NUMS;
        float gx = sm.fin.gm[tid][0], gy = sm.fin.gm[tid][1], gz = sm.fin.gm[tid][2];
        float bd = 3.4e38f; int bj = 0;
        for (int gg = 0; gg < G_NUMS; gg++) {
            if (gg == gg0) continue;
            int o = bb * G_NUMS + gg;
            float dx = gx - sm.fin.gm[o][0];
            float dy = gy - sm.fin.gm[o][1];
            float dz = gz - sm.fin.gm[o][2];
            float d = dx * dx + dy * dy + dz * dz;
            if (d < bd) { bd = d; bj = gg; }
        }
        int o = bb * G_NUMS + bj;
        float cosv = sm.fin.dir[tid][0] * sm.fin.dir[o][0] +
                     sm.fin.dir[tid][1] * sm.fin.dir[o][1] +
                     sm.fin.dir[tid][2] * sm.fin.dir[o][2];
        st = 1.f - cosv * cosv;
    }

    float e = et, s2v = st;
#pragma unroll
    for (int off = 32; off > 0; off >>= 1) {
        e += __shfl_down(e, off);
        s2v += __shfl_down(s2v, off);
    }
    if (lane == 0) { sm.fin.pe[wid] = e; sm.fin.ps[wid] = s2v; }
    __syncthreads();
    if (tid == 0) {
        float se = 0.f, ss = 0.f;
        for (int w = 0; w < NWAVES; w++) { se += sm.fin.pe[w]; ss += sm.fin.ps[w]; }
        out[0] = -se / (float)B + ss / (float)NG;
    }
}

// AoS -> int8 SoA planes. Sets OOR flag (syncw[1]) if any coord leaves [-8,8).
__global__ __launch_bounds__(256)
void quant_kernel(const float* __restrict__ pts,
                  uchar_t* __restrict__ xq, uchar_t* __restrict__ yq,
                  uchar_t* __restrict__ zq, unsigned* __restrict__ syncw,
                  int total4) {
    int t = blockIdx.x * 256 + threadIdx.x;
    if (t >= total4) return;
    const float4* __restrict__ P4 = (const float4*)pts;
    float4 f0 = P4[3 * t + 0];
    float4 f1 = P4[3 * t + 1];
    float4 f2 = P4[3 * t + 2];
    float xs[4] = {f0.x, f0.w, f1.z, f2.y};
    float ys[4] = {f0.y, f1.x, f1.w, f2.z};
    float zs[4] = {f0.z, f1.y, f2.x, f2.w};
    unsigned xb = 0, yb = 0, zb = 0; int bad = 0;
#pragma unroll
    for (int j = 0; j < 4; ++j) {
        int ix = (int)floorf((xs[j] + 8.0f) * 16.0f);
        int iy = (int)floorf((ys[j] + 8.0f) * 16.0f);
        int iz = (int)floorf((zs[j] + 8.0f) * 16.0f);
        if ((unsigned)ix > 255u || (unsigned)iy > 255u || (unsigned)iz > 255u) bad = 1;
        ix = ix < 0 ? 0 : (ix > 255 ? 255 : ix);
        iy = iy < 0 ? 0 : (iy > 255 ? 255 : iy);
        iz = iz < 0 ? 0 : (iz > 255 ? 255 : iz);
        xb |= (unsigned)ix << (8 * j);
        yb |= (unsigned)iy << (8 * j);
        zb |= (unsigned)iz << (8 * j);
    }
    ((unsigned*)xq)[t] = xb;
    ((unsigned*)yq)[t] = yb;
    ((unsigned*)zq)[t] = zb;
    if (bad) atomicOr(&syncw[1], 1u);
}

extern "C" void kernel_launch(void* const* d_in, const int* in_sizes, int n_in,
                              void* d_out, int out_size, void* d_ws, size_t ws_size,
                              hipStream_t stream) {
    const float* pts = (const float*)d_in[0];
    float* out = (float*)d_out;
    float* ws = (float*)d_ws;
    int B = in_sizes[0] / (N_PTS * 3);   // 8
    int nblk = B * G_NUMS;               // 240

    float* gmeans = ws;                                  // 3*nblk floats
    float* covs = ws + (size_t)3 * nblk;                 // 6*nblk floats
    unsigned* syncw = (unsigned*)(ws + (size_t)9 * nblk);   // 16 u32
    size_t plane_off = ((size_t)9 * nblk + 16) * 4;         // bytes
    plane_off = (plane_off + 15) & ~(size_t)15;             // 16B align
    uchar_t* xq = (uchar_t*)d_ws + plane_off;
    size_t planeB = (size_t)B * N_PTS;                      // 1 MB per plane
    uchar_t* yq = xq + planeB;
    uchar_t* zq = yq + planeB;
    size_t need = plane_off + 3 * planeB;
    const int use_q = ws_size >= need;

    hipMemsetAsync(syncw, 0, 64, stream);    // zero elect + OOR flag

    dim3 grid(nblk);
    if (use_q) {
        int total4 = B * N_PTS / 4;
        quant_kernel<<<dim3((total4 + 255) / 256), dim3(256), 0, stream>>>(
            pts, xq, yq, zq, syncw, total4);
        fused_knn_kernel<1><<<grid, dim3(TPB), 0, stream>>>(
            pts, xq, yq, zq, gmeans, covs, out, syncw, B, nblk);
    } else {
        fused_knn_kernel<0><<<grid, dim3(TPB), 0, stream>>>(
            pts, nullptr, nullptr, nullptr, gmeans, covs, out, syncw, B, nblk);
    }
}